// Round 5
// baseline (155.251 us; speedup 1.0000x reference)
//
#include <hip/hip_runtime.h>
#include <hip/hip_bf16.h>

// 2-bit quantized embedding gather, split into two streaming kernels.
// VOCAB=400000, DIM=128, NBITS=2 -> token t owns 8 aligned int32 words
// bit_arr[8t..8t+7] (32B, 16B-aligned); dim d -> word 8t + d/16, 2-bit code.
//
// R4 (split gather out of the 134MB-store kernel): 163.8 -> 152.5 us.
// R5: vectorize kernel A to int4 (one thread per half-token moves 16B,
// 4x fewer loads/stores, 16B-granular L3 reads); nontemporal stores in B
// (134MB write-once stream, keep L2 for bits/ws).

#define EMB_DIM 128

typedef float vfloat4 __attribute__((ext_vector_type(4)));
typedef int   vint4   __attribute__((ext_vector_type(4)));

// --- Kernel A: gather packed words into output order, 16B per thread -----
__global__ __launch_bounds__(256) void gather_words_kernel(
    const int* __restrict__ ids,      // [n_tokens]
    const int* __restrict__ bits,     // [3,200,000]
    int* __restrict__ ws_words,       // [n_tokens*8]
    int n_half)                       // n_tokens*2
{
    int i = blockIdx.x * blockDim.x + threadIdx.x;
    if (i >= n_half) return;
    int tok = ids[i >> 1];                    // 2 lanes share one id
    int off = (i & 1) * 4;                    // first/second int4 of the row
    vint4 w = *reinterpret_cast<const vint4*>(bits + (long long)tok * 8 + off);
    *reinterpret_cast<vint4*>(ws_words + (long long)i * 4) = w;
}

// --- Kernel B: pure linear decode + nontemporal store --------------------
__global__ __launch_bounds__(256) void decode_kernel(
    const int* __restrict__ ws_words, // [n_tokens*8], already in output order
    const float* __restrict__ cb,     // [4]
    float* __restrict__ out,          // [n_tokens*128] fp32
    int n_items)                      // n_tokens*32 (one float4 per item)
{
    int i = blockIdx.x * blockDim.x + threadIdx.x;
    if (i >= n_items) return;

    int word = ws_words[i >> 2];              // linear: 4 lanes share a word
    int byte = (word >> ((i & 3) * 8)) & 0xff;

    float c0 = cb[0], c1 = cb[1], c2 = cb[2], c3 = cb[3];

    vfloat4 r;
#pragma unroll
    for (int q = 0; q < 4; ++q) {
        int c    = (byte >> (2 * q)) & 3;
        float lo = (c & 1) ? c1 : c0;
        float hi = (c & 1) ? c3 : c2;
        r[q]     = (c & 2) ? hi : lo;         // 2x v_cndmask per element
    }
    // out offset = i*4 floats: consecutive lanes -> contiguous 1KiB/wave.
    __builtin_nontemporal_store(
        r, reinterpret_cast<vfloat4*>(out + (size_t)i * 4));
}

// --- Fallback fused kernel (only if ws too small) ------------------------
__global__ __launch_bounds__(256) void fused_kernel(
    const int* __restrict__ ids, const int* __restrict__ bits,
    const float* __restrict__ cb, float* __restrict__ out, int n_items)
{
    int i = blockIdx.x * blockDim.x + threadIdx.x;
    if (i >= n_items) return;
    int t = i >> 5, k = i & 31;
    int tok  = ids[t];
    int word = bits[(long long)tok * 8 + (k >> 2)];
    int byte = (word >> ((k & 3) * 8)) & 0xff;
    float c0 = cb[0], c1 = cb[1], c2 = cb[2], c3 = cb[3];
    vfloat4 r;
#pragma unroll
    for (int q = 0; q < 4; ++q) {
        int c = (byte >> (2 * q)) & 3;
        float lo = (c & 1) ? c1 : c0;
        float hi = (c & 1) ? c3 : c2;
        r[q] = (c & 2) ? hi : lo;
    }
    *reinterpret_cast<vfloat4*>(out + (size_t)i * 4) = r;
}

extern "C" void kernel_launch(void* const* d_in, const int* in_sizes, int n_in,
                              void* d_out, int out_size, void* d_ws, size_t ws_size,
                              hipStream_t stream) {
    const int*   ids  = (const int*)d_in[0];
    const int*   bits = (const int*)d_in[1];
    const float* cb   = (const float*)d_in[2];
    float*       out  = (float*)d_out;

    int n_tokens = in_sizes[0];               // 262,144
    int n_half   = n_tokens * 2;              // 524,288 (16B movers)
    int n_words  = n_tokens * 8;              // 2,097,152
    int n_items  = n_tokens * 32;             // 8,388,608
    int block = 256;

    if (ws_size >= (size_t)n_words * sizeof(int)) {
        int* ws_words = (int*)d_ws;
        gather_words_kernel<<<(n_half + block - 1) / block, block, 0, stream>>>(
            ids, bits, ws_words, n_half);
        decode_kernel<<<(n_items + block - 1) / block, block, 0, stream>>>(
            ws_words, cb, out, n_items);
    } else {
        fused_kernel<<<(n_items + block - 1) / block, block, 0, stream>>>(
            ids, bits, cb, out, n_items);
    }
}

// Round 6
// 149.532 us; speedup vs baseline: 1.0382x; 1.0382x over previous
//
#include <hip/hip_runtime.h>
#include <hip/hip_bf16.h>

// 2-bit quantized embedding gather, single kernel with per-block LDS staging.
// VOCAB=400000, DIM=128, NBITS=2 -> token t owns 8 aligned int32 words
// bit_arr[8t..8t+7] (32B row); dim d -> word 8t + d/16, 2-bit code,
// out = codebook[code].
//
// History: fused 1-thread/item 166.7us (R1) -> fused 4-deep batch 163.8 (R3)
// -> split gather/decode via ws 152.5 (R4) -> +int4/+nt 155.3 (R5, nt hurt).
// R6: keep R4's gather/store decoupling but stage in LDS instead of the ws
// round-trip (saves 17MB traffic + 1 launch + cross-XCD dirty-ws reads).
// Block = 256 thr handles 64 tokens: phase 1 gathers 64 rows (2KB) into LDS
// via 128 int4 loads; phase 2 decodes 8 float4 items/thread and writes one
// contiguous 32KB chunk. 2KB LDS + low VGPR -> ~8 blocks/CU resident, so
// barrier/gather latency is cross-block hidden (m114 co-scheduling).

#define EMB_DIM 128
#define TOK_PER_BLOCK 64
#define BLOCK 256

typedef float vfloat4 __attribute__((ext_vector_type(4)));
typedef int   vint4   __attribute__((ext_vector_type(4)));

__global__ __launch_bounds__(BLOCK) void embed2bit_lds_kernel(
    const int* __restrict__ ids,      // [n_tokens] int32
    const int* __restrict__ bits,     // [3,200,000] packed int32
    const float* __restrict__ cb,     // [4] codebook
    float* __restrict__ out,          // [n_tokens, 128] fp32
    int n_tokens)
{
    __shared__ int lds_words[TOK_PER_BLOCK * 8];   // 2 KB: rows in token order

    const int t0  = blockIdx.x * TOK_PER_BLOCK;
    const int tid = threadIdx.x;

    // --- Phase 1: gather 64 token rows into LDS (128 threads x int4) -----
    if (tid < TOK_PER_BLOCK * 2) {
        int t = t0 + (tid >> 1);                  // 2 threads per token
        if (t < n_tokens) {
            int tok = ids[t];
            vint4 w = *reinterpret_cast<const vint4*>(
                bits + (long long)tok * 8 + (tid & 1) * 4);
            *reinterpret_cast<vint4*>(&lds_words[tid * 4]) = w;
        }
    }
    __syncthreads();

    // --- Phase 2: decode + contiguous stores (8 float4 items / thread) ---
    const float c0 = cb[0], c1 = cb[1], c2 = cb[2], c3 = cb[3];
    const long long out_base = (long long)t0 * EMB_DIM;
    const int n_items = (n_tokens - t0 >= TOK_PER_BLOCK
                             ? TOK_PER_BLOCK : n_tokens - t0) * 32;

#pragma unroll
    for (int q = 0; q < 8; ++q) {
        int item = q * BLOCK + tid;               // [0, 2048)
        if (item >= n_items) break;
        int word = lds_words[item >> 2];          // 4 lanes broadcast a word
        int byte = (word >> ((item & 3) * 8)) & 0xff;

        vfloat4 r;
#pragma unroll
        for (int j = 0; j < 4; ++j) {
            int c    = (byte >> (2 * j)) & 3;
            float lo = (c & 1) ? c1 : c0;
            float hi = (c & 1) ? c3 : c2;
            r[j]     = (c & 2) ? hi : lo;         // 2x v_cndmask per element
        }
        // item*16B: consecutive lanes -> contiguous 4KB per wave-store.
        *reinterpret_cast<vfloat4*>(out + out_base + (long long)item * 4) = r;
    }
}

extern "C" void kernel_launch(void* const* d_in, const int* in_sizes, int n_in,
                              void* d_out, int out_size, void* d_ws, size_t ws_size,
                              hipStream_t stream) {
    const int*   ids  = (const int*)d_in[0];
    const int*   bits = (const int*)d_in[1];
    const float* cb   = (const float*)d_in[2];
    float*       out  = (float*)d_out;

    int n_tokens = in_sizes[0];                   // 262,144
    int grid = (n_tokens + TOK_PER_BLOCK - 1) / TOK_PER_BLOCK;   // 4096

    embed2bit_lds_kernel<<<grid, BLOCK, 0, stream>>>(ids, bits, cb, out, n_tokens);
}